// Round 1
// baseline (240.092 us; speedup 1.0000x reference)
//
#include <hip/hip_runtime.h>

// UFO linear attention, MI355X (gfx950). B=8, N=4096, C=512, H=8, DK=DV=64.
//
// R4: occupancy fix for the GEMM core. rocprof showed proj_qkv at
// MfmaUtil 16% / Occupancy 20% / HBM 10% -> latency-bound at 2 blocks/CU
// (64 KB LDS double-buffer). New core: As single-buffered + Bs
// double-buffered (48 KB total), 1-deep EARLY register prefetch (issue
// t+1 loads before COMPUTE(t); consume after -> all waitcnts are
// compiler-counted reg-dep waits, no manual vmcnt drains), 2 raw
// barriers per K-tile, __launch_bounds__(256,3) -> 3 blocks/CU.

typedef __attribute__((ext_vector_type(4))) float f32x4;
typedef __attribute__((ext_vector_type(8))) short s16x8;
typedef __attribute__((ext_vector_type(4))) unsigned short u16x4;
typedef __attribute__((ext_vector_type(8))) unsigned short u16x8;

#define DEVFN __device__ __forceinline__

DEVFN unsigned short f2b(float f) {  // fp32 -> bf16 RNE
  union { float f; unsigned u; } un; un.f = f;
  unsigned r = un.u + 0x7fffu + ((un.u >> 16) & 1u);
  return (unsigned short)(r >> 16);
}
DEVFN float b2f(unsigned short us) {
  union { unsigned u; float f; } un; un.u = ((unsigned)us) << 16;
  return un.f;
}

// ---------------------------------------------------------------------------
// Core GEMM: C[m][n] = sum_k A[m][k]*Bt[n][k] + bias[n]; optional fused
// head-norm. M = grid, N = K = 512. 128x128 tile, BK=64, 4 waves.
// LDS 48 KB: As[1] (16 KB) + Bs[2] (32 KB) -> 3 blocks/CU.
// ---------------------------------------------------------------------------
template <bool AF32, typename CT>
DEVFN void gemm_core(const void* Ain, const unsigned short* Bt,
                     const float* bias, CT* C, bool qnorm, const float* gamma,
                     int bx, int by) {
  constexpr int KK = 512, NN = 512;
  __shared__ unsigned short As[128 * 64];       // single-buffered, swizzled
  __shared__ unsigned short Bs[2][128 * 64];    // double-buffered, swizzled
  const int tid = threadIdx.x, lane = tid & 63, wid = tid >> 6;
  const int wm = (wid >> 1) * 64, wn = (wid & 1) * 64;
  const int r = lane & 15, g = lane >> 4;

  const float* Af = nullptr;
  const unsigned short* Ab = nullptr;
  if constexpr (AF32)
    Af = (const float*)Ain + (long)(bx * 128 + (tid >> 4)) * KK + (tid & 15) * 4;
  else
    Ab = (const unsigned short*)Ain + (long)(bx * 128 + (tid >> 3)) * KK + (tid & 7) * 8;
  const unsigned short* Bp = Bt + (long)(by * 128 + (tid >> 3)) * KK + (tid & 7) * 8;

  f32x4 PAf[8];
  u16x8 PAb[4];
  u16x8 PB[4];
  f32x4 acc[4][4] = {};

// Issue order: PB first, then PA -> consuming PB (WRITE_B, right after
// COMPUTE) leaves the 8 A-loads in flight across barrier #1.
#define ISSUE(KT)                                                              \
  {                                                                            \
    _Pragma("unroll") for (int i = 0; i < 4; ++i)                              \
        PB[i] = *reinterpret_cast<const u16x8*>(                               \
            Bp + (long)i * 32 * KK + (KT)*64);                                 \
    if constexpr (AF32) {                                                      \
      _Pragma("unroll") for (int i = 0; i < 8; ++i)                            \
          PAf[i] = *reinterpret_cast<const f32x4*>(                            \
              Af + (long)i * 16 * KK + (KT)*64);                               \
    } else {                                                                   \
      _Pragma("unroll") for (int i = 0; i < 4; ++i)                            \
          PAb[i] = *reinterpret_cast<const u16x8*>(                            \
              Ab + (long)i * 32 * KK + (KT)*64);                               \
    }                                                                          \
  }

#define WRITE_A                                                                \
  {                                                                            \
    if constexpr (AF32) {                                                      \
      const int rr = tid >> 4, cb = (tid & 15) * 8;                            \
      _Pragma("unroll") for (int i = 0; i < 8; ++i) {                          \
        int row = i * 16 + rr;                                                 \
        int off = row * 128 + (cb ^ ((row & 7) << 4));                         \
        u16x4 o = {f2b(PAf[i][0]), f2b(PAf[i][1]),                             \
                   f2b(PAf[i][2]), f2b(PAf[i][3])};                            \
        *reinterpret_cast<u16x4*>(reinterpret_cast<char*>(As) + off) = o;      \
      }                                                                        \
    } else {                                                                   \
      const int rr = tid >> 3, cb = (tid & 7) * 16;                            \
      _Pragma("unroll") for (int i = 0; i < 4; ++i) {                          \
        int row = i * 32 + rr;                                                 \
        int off = row * 128 + (cb ^ ((row & 7) << 4));                         \
        *reinterpret_cast<u16x8*>(reinterpret_cast<char*>(As) + off) = PAb[i]; \
      }                                                                        \
    }                                                                          \
  }

#define WRITE_B(BUF)                                                           \
  {                                                                            \
    const int rr = tid >> 3, cb = (tid & 7) * 16;                              \
    _Pragma("unroll") for (int i = 0; i < 4; ++i) {                            \
      int row = i * 32 + rr;                                                   \
      int off = row * 128 + (cb ^ ((row & 7) << 4));                           \
      *reinterpret_cast<u16x8*>(reinterpret_cast<char*>(Bs[BUF]) + off) =      \
          PB[i];                                                               \
    }                                                                          \
  }

#define COMPUTE(BBUF)                                                          \
  {                                                                            \
    _Pragma("unroll") for (int ks = 0; ks < 2; ++ks) {                         \
      s16x8 a[4], b[4];                                                        \
      const int kb = ks * 64 + g * 16;                                         \
      _Pragma("unroll") for (int i = 0; i < 4; ++i) {                          \
        int ar = wm + i * 16 + r;                                              \
        a[i] = *reinterpret_cast<const s16x8*>(                                \
            reinterpret_cast<const char*>(As) + ar * 128 +                     \
            (kb ^ ((ar & 7) << 4)));                                           \
        int br = wn + i * 16 + r;                                              \
        b[i] = *reinterpret_cast<const s16x8*>(                                \
            reinterpret_cast<const char*>(Bs[BBUF]) + br * 128 +               \
            (kb ^ ((br & 7) << 4)));                                           \
      }                                                                        \
      _Pragma("unroll") for (int i = 0; i < 4; ++i)                            \
          _Pragma("unroll") for (int j = 0; j < 4; ++j) acc[i][j] =            \
          __builtin_amdgcn_mfma_f32_16x16x32_bf16(a[i], b[j], acc[i][j], 0,    \
                                                  0, 0);                       \
    }                                                                          \
  }

#define SB0 __builtin_amdgcn_sched_barrier(0);
// barrier #1: no waitcnt needed -- COMPUTE's ds_reads were consumed by the
// MFMAs before any wave reaches it; WRITE_B's ds_writes may stay in flight.
#define BAR_RAW                                                                \
  SB0 __builtin_amdgcn_s_barrier(); SB0
// barrier #2: own ds_writes (A and B) must land before anyone reads them.
#define LGKM_BAR                                                               \
  asm volatile("s_waitcnt lgkmcnt(0)" ::: "memory");                           \
  SB0 __builtin_amdgcn_s_barrier(); SB0

  // prologue: tile 0 -> regs -> LDS (Bs[0], As)
  ISSUE(0)
  WRITE_B(0)
  WRITE_A
  LGKM_BAR
  // Steady state per tile t:
  //   ISSUE(t+1)          (loads fly under COMPUTE)
  //   COMPUTE(t)          reads As + Bs[t&1]
  //   WRITE_B -> Bs[(t+1)&1]   (other buffer: no race with readers)
  //   BAR_RAW             (As now free)
  //   WRITE_A -> As
  //   LGKM_BAR            (stage visible to all)
  // t=0
  ISSUE(1) SB0 COMPUTE(0) WRITE_B(1) BAR_RAW WRITE_A LGKM_BAR
  // t=1
  ISSUE(2) SB0 COMPUTE(1) WRITE_B(0) BAR_RAW WRITE_A LGKM_BAR
  // t=2
  ISSUE(3) SB0 COMPUTE(0) WRITE_B(1) BAR_RAW WRITE_A LGKM_BAR
  // t=3
  ISSUE(4) SB0 COMPUTE(1) WRITE_B(0) BAR_RAW WRITE_A LGKM_BAR
  // t=4
  ISSUE(5) SB0 COMPUTE(0) WRITE_B(1) BAR_RAW WRITE_A LGKM_BAR
  // t=5
  ISSUE(6) SB0 COMPUTE(1) WRITE_B(0) BAR_RAW WRITE_A LGKM_BAR
  // t=6
  ISSUE(7) SB0 COMPUTE(0) WRITE_B(1) BAR_RAW WRITE_A LGKM_BAR
  // t=7
  COMPUTE(1)

#undef ISSUE
#undef WRITE_A
#undef WRITE_B
#undef COMPUTE
#undef BAR_RAW
#undef LGKM_BAR
#undef SB0

  // ---- epilogue (C/D layout: col=lane&15, row=(lane>>4)*4+ii) ----
  const int crow0 = bx * 128 + wm + g * 4;
  const int ccol0 = by * 128 + wn + r;
#pragma unroll
  for (int j = 0; j < 4; ++j) {
    float bv = bias[ccol0 + j * 16];
#pragma unroll
    for (int i = 0; i < 4; ++i)
#pragma unroll
      for (int ii = 0; ii < 4; ++ii) acc[i][j][ii] += bv;
  }
  if (qnorm) {  // wave's 64 cols == one head; L2-norm over them per row
    const int h = (by * 128 + wn) >> 6;
    const float gam = gamma[h];
#pragma unroll
    for (int i = 0; i < 4; ++i)
#pragma unroll
      for (int ii = 0; ii < 4; ++ii) {
        float s = 0.f;
#pragma unroll
        for (int j = 0; j < 4; ++j) s += acc[i][j][ii] * acc[i][j][ii];
        s += __shfl_xor(s, 1);
        s += __shfl_xor(s, 2);
        s += __shfl_xor(s, 4);
        s += __shfl_xor(s, 8);
        float sc = gam / sqrtf(s);
#pragma unroll
        for (int j = 0; j < 4; ++j) acc[i][j][ii] *= sc;
      }
  }
#pragma unroll
  for (int i = 0; i < 4; ++i)
#pragma unroll
    for (int j = 0; j < 4; ++j)
#pragma unroll
      for (int ii = 0; ii < 4; ++ii) {
        long row = crow0 + i * 16 + ii;
        int col = ccol0 + j * 16;
        if constexpr (sizeof(CT) == 2)
          C[row * NN + col] = f2b(acc[i][j][ii]);
        else
          C[row * NN + col] = acc[i][j][ii];
      }
}

// y-inner + XCD-chunked bijective swizzle; NWG must be a multiple of 32.
DEVFN void swz_xy(int bid, int nwg, int& bx, int& by) {
  int s = (bid & 7) * (nwg >> 3) + (bid >> 3);
  bx = s >> 2;
  by = s & 3;
}

__global__ __launch_bounds__(256, 3)
void proj_qkv(const float* __restrict__ Aq, const float* __restrict__ Ak,
              const float* __restrict__ Av, const unsigned short* __restrict__ Bq,
              const unsigned short* __restrict__ Bk, const unsigned short* __restrict__ Bv,
              const float* __restrict__ bq, const float* __restrict__ bk,
              const float* __restrict__ bv, unsigned short* __restrict__ Cq,
              unsigned short* __restrict__ Ck, unsigned short* __restrict__ Cv,
              const float* __restrict__ gamma) {
  const int z = blockIdx.z;
  const float* A = z == 0 ? Aq : (z == 1 ? Ak : Av);
  const unsigned short* B = z == 0 ? Bq : (z == 1 ? Bk : Bv);
  const float* bias = z == 0 ? bq : (z == 1 ? bk : bv);
  unsigned short* C = z == 0 ? Cq : (z == 1 ? Ck : Cv);
  int bx, by;
  swz_xy(blockIdx.x, 1024, bx, by);
  gemm_core<true, unsigned short>(A, B, bias, C, z == 0, gamma, bx, by);
}

__global__ __launch_bounds__(256, 3)
void gemm_final(const unsigned short* __restrict__ q, const unsigned short* __restrict__ Mt,
                const float* __restrict__ bo, float* __restrict__ out) {
  const int zb = blockIdx.z;
  int bx, by;
  swz_xy(blockIdx.x, 128, bx, by);
  gemm_core<false, float>(q + (long)zb * 2097152, Mt + (long)zb * 262144, bo,
                          out + (long)zb * 2097152, false, nullptr, bx, by);
}

// ---------------------------------------------------------------------------
// kv partials: part[chunk][bh][dk][dv] = sum over 256 n of k outer v
// ---------------------------------------------------------------------------
#define NCHUNK 16
__global__ __launch_bounds__(256, 2)
void kv_partial(const unsigned short* __restrict__ kq,
                const unsigned short* __restrict__ vq,
                float* __restrict__ part) {
  const int tid = threadIdx.x;
  const int chunk = blockIdx.x;
  const int bh = blockIdx.y;
  const int b = bh >> 3, h = bh & 7;
  __shared__ float ks[32][64];
  __shared__ float vs[32][64];
  const int dk0 = (tid & 15) * 4;
  const int dv0 = (tid >> 4) * 4;
  float acc[4][4] = {};
  const long nbase = (long)b * 4096 + chunk * 256;

  for (int sub = 0; sub < 8; ++sub) {
    long n0 = nbase + sub * 32;
#pragma unroll
    for (int i = 0; i < 2; ++i) {
      int e = i * 256 + tid;
      int row = e >> 4, c4 = e & 15;
      long gofs = (n0 + row) * 512 + h * 64 + c4 * 4;
      u16x4 kk = *reinterpret_cast<const u16x4*>(kq + gofs);
      u16x4 vv = *reinterpret_cast<const u16x4*>(vq + gofs);
      f32x4 kf = {b2f(kk[0]), b2f(kk[1]), b2f(kk[2]), b2f(kk[3])};
      f32x4 vf = {b2f(vv[0]), b2f(vv[1]), b2f(vv[2]), b2f(vv[3])};
      *reinterpret_cast<f32x4*>(&ks[row][c4 * 4]) = kf;
      *reinterpret_cast<f32x4*>(&vs[row][c4 * 4]) = vf;
    }
    __syncthreads();
#pragma unroll 4
    for (int n = 0; n < 32; ++n) {
      f32x4 kk = *reinterpret_cast<const f32x4*>(&ks[n][dk0]);
      f32x4 vv = *reinterpret_cast<const f32x4*>(&vs[n][dv0]);
#pragma unroll
      for (int a = 0; a < 4; ++a)
#pragma unroll
        for (int c = 0; c < 4; ++c)
          acc[a][c] += kk[a] * vv[c];
    }
    __syncthreads();
  }
  float* pg = part + ((long)chunk * 64 + bh) * 4096;
#pragma unroll
  for (int a = 0; a < 4; ++a) {
    f32x4 o = {acc[a][0], acc[a][1], acc[a][2], acc[a][3]};
    *reinterpret_cast<f32x4*>(pg + (dk0 + a) * 64 + dv0) = o;
  }
}

// reduce partials + L2-norm rows (over dv) * gamma -> kvn bf16 [bh][64][64]
__global__ __launch_bounds__(256)
void kv_normN(const float* __restrict__ part, const float* __restrict__ gamma,
              unsigned short* __restrict__ kvn) {
  const int bh = blockIdx.x, h = bh & 7;
  const int tid = threadIdx.x;
  __shared__ float kvs[4096];
  __shared__ float scale[64];
#pragma unroll
  for (int i = 0; i < 4; ++i) {
    int e4 = i * 256 + tid;
    const float* p = part + (long)bh * 4096 + e4 * 4;
    f32x4 s = {0.f, 0.f, 0.f, 0.f};
#pragma unroll
    for (int c = 0; c < NCHUNK; ++c) {
      f32x4 v = *reinterpret_cast<const f32x4*>(p + (long)c * 64 * 4096);
      s += v;
    }
    *reinterpret_cast<f32x4*>(kvs + e4 * 4) = s;
  }
  __syncthreads();
  if (tid < 64) {
    float s = 0.f;
    for (int dv = 0; dv < 64; ++dv) { float x = kvs[tid * 64 + dv]; s += x * x; }
    scale[tid] = gamma[h] / sqrtf(s);
  }
  __syncthreads();
#pragma unroll
  for (int i = 0; i < 4; ++i) {
    int e4 = i * 256 + tid;
    float sc = scale[e4 >> 4];
    f32x4 v = *reinterpret_cast<const f32x4*>(kvs + e4 * 4);
    u16x4 o = {f2b(v[0] * sc), f2b(v[1] * sc), f2b(v[2] * sc), f2b(v[3] * sc)};
    *reinterpret_cast<u16x4*>(kvn + (long)bh * 4096 + e4 * 4) = o;
  }
}

// Mt[b][c][h*64+dk] = sum_dv Wo[c][h*64+dv] * kvn[b,h][dk][dv]
__global__ __launch_bounds__(64)
void mt_kernel(const unsigned short* __restrict__ Wo_b,
               const unsigned short* __restrict__ kvn,
               unsigned short* __restrict__ Mt) {
  const int bid = blockIdx.x;
  const int bh = bid >> 2, seg = bid & 3;
  const int b = bh >> 3, h = bh & 7;
  const int lane = threadIdx.x;
  const int r = lane & 15, g = lane >> 4;
  f32x4 acc[8][4] = {};
  s16x8 bf[2][4];
#pragma unroll
  for (int ks = 0; ks < 2; ++ks)
#pragma unroll
    for (int j = 0; j < 4; ++j)
      bf[ks][j] = *reinterpret_cast<const s16x8*>(
          kvn + (long)bh * 4096 + (j * 16 + r) * 64 + ks * 32 + g * 8);
#pragma unroll
  for (int ks = 0; ks < 2; ++ks)
#pragma unroll
    for (int i = 0; i < 8; ++i) {
      s16x8 af = *reinterpret_cast<const s16x8*>(
          Wo_b + (long)(seg * 128 + i * 16 + r) * 512 + h * 64 + ks * 32 + g * 8);
#pragma unroll
      for (int j = 0; j < 4; ++j)
        acc[i][j] = __builtin_amdgcn_mfma_f32_16x16x32_bf16(af, bf[ks][j], acc[i][j], 0, 0, 0);
    }
#pragma unroll
  for (int i = 0; i < 8; ++i)
#pragma unroll
    for (int j = 0; j < 4; ++j)
#pragma unroll
      for (int ii = 0; ii < 4; ++ii) {
        int c = seg * 128 + i * 16 + g * 4 + ii;
        int dk = j * 16 + r;
        Mt[(long)b * 262144 + (long)c * 512 + h * 64 + dk] = f2b(acc[i][j][ii]);
      }
}

__global__ void cast4(const float* __restrict__ a0, const float* __restrict__ a1,
                      const float* __restrict__ a2, const float* __restrict__ a3,
                      unsigned short* __restrict__ o0, unsigned short* __restrict__ o1,
                      unsigned short* __restrict__ o2, unsigned short* __restrict__ o3) {
  const int y = blockIdx.y;
  const float* in = y == 0 ? a0 : (y == 1 ? a1 : (y == 2 ? a2 : a3));
  unsigned short* out = y == 0 ? o0 : (y == 1 ? o1 : (y == 2 ? o2 : o3));
  int i = blockIdx.x * 256 + threadIdx.x;
  f32x4 v = reinterpret_cast<const f32x4*>(in)[i];
  reinterpret_cast<u16x4*>(out)[i] = u16x4{f2b(v[0]), f2b(v[1]), f2b(v[2]), f2b(v[3])};
}

// ---------------------------------------------------------------------------
extern "C" void kernel_launch(void* const* d_in, const int* in_sizes, int n_in,
                              void* d_out, int out_size, void* d_ws, size_t ws_size,
                              hipStream_t stream) {
  const float* queries = (const float*)d_in[0];
  const float* keys    = (const float*)d_in[1];
  const float* values  = (const float*)d_in[2];
  const float* Wq = (const float*)d_in[3];
  const float* bq = (const float*)d_in[4];
  const float* Wk = (const float*)d_in[5];
  const float* bk = (const float*)d_in[6];
  const float* Wv = (const float*)d_in[7];
  const float* bv = (const float*)d_in[8];
  const float* Wo = (const float*)d_in[9];
  const float* bo = (const float*)d_in[10];
  const float* gamma = (const float*)d_in[11];

  unsigned short* Wq_b = (unsigned short*)d_ws;            // 512 KB each
  unsigned short* Wk_b = Wq_b + 262144;
  unsigned short* Wv_b = Wk_b + 262144;
  unsigned short* Wo_b = Wv_b + 262144;
  unsigned short* q_b  = Wo_b + 262144;                    // 32 MB (holds q_n)
  unsigned short* kvn  = q_b + 16777216;                   // 512 KB
  float* part = (float*)(kvn + 262144);                    // 16 MB
  unsigned short* Mt = (unsigned short*)part;              // 4 MB (part dead by then)
  unsigned short* k_b = (unsigned short*)d_out;            // d_out scratch
  unsigned short* v_b = k_b + 16777216;
  float* out = (float*)d_out;

  cast4<<<dim3(256, 4), 256, 0, stream>>>(Wq, Wk, Wv, Wo, Wq_b, Wk_b, Wv_b, Wo_b);

  proj_qkv<<<dim3(1024, 1, 3), 256, 0, stream>>>(
      queries, keys, values, Wq_b, Wk_b, Wv_b, bq, bk, bv, q_b, k_b, v_b, gamma);

  kv_partial<<<dim3(NCHUNK, 64), 256, 0, stream>>>(k_b, v_b, part);
  kv_normN<<<64, 256, 0, stream>>>(part, gamma, kvn);
  mt_kernel<<<256, 64, 0, stream>>>(Wo_b, kvn, Mt);

  gemm_final<<<dim3(128, 1, 8), 256, 0, stream>>>(q_b, Mt, bo, out);
}

// Round 2
// 185.843 us; speedup vs baseline: 1.2919x; 1.2919x over previous
//
#include <hip/hip_runtime.h>

// UFO linear attention, MI355X (gfx950). B=8, N=4096, C=512, H=8, DK=DV=64.
//
// R5: fix R4's spill (VGPR split 85/85 arch/AGPR at 3 blocks/CU left no room
// for 48 reg-staged prefetch regs -> 100 MB/dispatch scratch traffic).
// B staging now uses global_load_lds (async, 0 staging regs, loads in
// flight across barriers); swizzled LDS layout kept via pre-swizzled
// per-lane global source + linear LDS dest. A stays reg-staged 1-deep
// (fp32->bf16 convert path). LDS 48 KB, __launch_bounds__(256,3).

typedef __attribute__((ext_vector_type(4))) float f32x4;
typedef __attribute__((ext_vector_type(8))) short s16x8;
typedef __attribute__((ext_vector_type(4))) unsigned short u16x4;
typedef __attribute__((ext_vector_type(8))) unsigned short u16x8;

#define DEVFN __device__ __forceinline__

DEVFN unsigned short f2b(float f) {  // fp32 -> bf16 RNE
  union { float f; unsigned u; } un; un.f = f;
  unsigned r = un.u + 0x7fffu + ((un.u >> 16) & 1u);
  return (unsigned short)(r >> 16);
}
DEVFN float b2f(unsigned short us) {
  union { unsigned u; float f; } un; un.u = ((unsigned)us) << 16;
  return un.f;
}

// async global->LDS, 16 B per lane; lds dest is wave-uniform base + lane*16
DEVFN void gl_lds16(const void* g, void* l) {
  __builtin_amdgcn_global_load_lds(
      (const __attribute__((address_space(1))) unsigned*)g,
      (__attribute__((address_space(3))) unsigned*)l, 16, 0, 0);
}

// ---------------------------------------------------------------------------
// Core GEMM: C[m][n] = sum_k A[m][k]*Bt[n][k] + bias[n]; optional fused
// head-norm. M = grid, N = K = 512. 128x128 tile, BK=64, 4 waves.
// LDS 48 KB: As[1] (16 KB, reg-staged) + Bs[2] (32 KB, global_load_lds).
// ---------------------------------------------------------------------------
template <bool AF32, typename CT>
DEVFN void gemm_core(const void* Ain, const unsigned short* Bt,
                     const float* bias, CT* C, bool qnorm, const float* gamma,
                     int bx, int by) {
  constexpr int KK = 512, NN = 512;
  __shared__ unsigned short As[128 * 64];       // single-buffered, swizzled
  __shared__ unsigned short Bs[2][128 * 64];    // double-buffered, swizzled
  const int tid = threadIdx.x, lane = tid & 63, wid = tid >> 6;
  const int wm = (wid >> 1) * 64, wn = (wid & 1) * 64;
  const int r = lane & 15, g = lane >> 4;

  const float* Af = nullptr;
  const unsigned short* Ab = nullptr;
  if constexpr (AF32)
    Af = (const float*)Ain + (long)(bx * 128 + (tid >> 4)) * KK + (tid & 15) * 4;
  else
    Ab = (const unsigned short*)Ain + (long)(bx * 128 + (tid >> 3)) * KK + (tid & 7) * 8;

  // B source for global_load_lds: chunk = wid*4+q covers rows
  // [chunk*8, chunk*8+8); lane l -> row chunk*8 + (l>>3), 16B col slot
  // swizzled: ((l&7) ^ (l>>3))*16  (row&7 == l>>3 since chunks are
  // 8-row aligned). LDS dest is linear: chunk*1024 + l*16.
  const char* Bsrc = (const char*)Bt +
                     ((long)(by * 128 + wid * 32 + (lane >> 3)) * (KK * 2)) +
                     (((lane & 7) ^ (lane >> 3)) * 16);

  f32x4 PAf[8];
  u16x8 PAb[4];
  f32x4 acc[4][4] = {};

#define ISSUE_A(KT)                                                            \
  {                                                                            \
    if constexpr (AF32) {                                                      \
      _Pragma("unroll") for (int i = 0; i < 8; ++i)                            \
          PAf[i] = *reinterpret_cast<const f32x4*>(                            \
              Af + (long)i * 16 * KK + (KT)*64);                               \
    } else {                                                                   \
      _Pragma("unroll") for (int i = 0; i < 4; ++i)                            \
          PAb[i] = *reinterpret_cast<const u16x8*>(                            \
              Ab + (long)i * 32 * KK + (KT)*64);                               \
    }                                                                          \
  }

#define STAGE_B(BUF, KT)                                                       \
  {                                                                            \
    _Pragma("unroll") for (int q = 0; q < 4; ++q)                              \
        gl_lds16(Bsrc + q * 8192 + (KT)*128,                                   \
                 (char*)Bs[BUF] + wid * 4096 + q * 1024);                      \
  }

#define WRITE_A                                                                \
  {                                                                            \
    if constexpr (AF32) {                                                      \
      const int rr = tid >> 4, cb = (tid & 15) * 8;                            \
      _Pragma("unroll") for (int i = 0; i < 8; ++i) {                          \
        int row = i * 16 + rr;                                                 \
        int off = row * 128 + (cb ^ ((row & 7) << 4));                         \
        u16x4 o = {f2b(PAf[i][0]), f2b(PAf[i][1]),                             \
                   f2b(PAf[i][2]), f2b(PAf[i][3])};                            \
        *reinterpret_cast<u16x4*>(reinterpret_cast<char*>(As) + off) = o;      \
      }                                                                        \
    } else {                                                                   \
      const int rr = tid >> 3, cb = (tid & 7) * 16;                            \
      _Pragma("unroll") for (int i = 0; i < 4; ++i) {                          \
        int row = i * 32 + rr;                                                 \
        int off = row * 128 + (cb ^ ((row & 7) << 4));                         \
        *reinterpret_cast<u16x8*>(reinterpret_cast<char*>(As) + off) = PAb[i]; \
      }                                                                        \
    }                                                                          \
  }

#define COMPUTE(BBUF)                                                          \
  {                                                                            \
    _Pragma("unroll") for (int ks = 0; ks < 2; ++ks) {                         \
      s16x8 a[4], b[4];                                                        \
      const int kb = ks * 64 + g * 16;                                         \
      _Pragma("unroll") for (int i = 0; i < 4; ++i) {                          \
        int ar = wm + i * 16 + r;                                              \
        a[i] = *reinterpret_cast<const s16x8*>(                                \
            reinterpret_cast<const char*>(As) + ar * 128 +                     \
            (kb ^ ((ar & 7) << 4)));                                           \
        int br = wn + i * 16 + r;                                              \
        b[i] = *reinterpret_cast<const s16x8*>(                                \
            reinterpret_cast<const char*>(Bs[BBUF]) + br * 128 +               \
            (kb ^ ((br & 7) << 4)));                                           \
      }                                                                        \
      _Pragma("unroll") for (int i = 0; i < 4; ++i)                            \
          _Pragma("unroll") for (int j = 0; j < 4; ++j) acc[i][j] =            \
          __builtin_amdgcn_mfma_f32_16x16x32_bf16(a[i], b[j], acc[i][j], 0,    \
                                                  0, 0);                       \
    }                                                                          \
  }

#define SB0 __builtin_amdgcn_sched_barrier(0);
// barrier #1 (after COMPUTE): all waves' As/Bs reads done (MFMAs consumed
// them before this point in program order); As is now free to overwrite.
#define BAR_RAW                                                                \
  SB0 __builtin_amdgcn_s_barrier(); SB0
// barrier #2 (end of tile): own A ds_writes (lgkm) + all B global_load_lds
// (vmcnt) must land before anyone reads the staged tile.
#define END_BAR                                                                \
  asm volatile("s_waitcnt vmcnt(0) lgkmcnt(0)" ::: "memory");                  \
  SB0 __builtin_amdgcn_s_barrier(); SB0

  // prologue: tile 0. A loads issued BEFORE B stage so consuming A regs
  // (in-order vmcnt) does not wait on the B loads.
  ISSUE_A(0)
  STAGE_B(0, 0)
  WRITE_A
  END_BAR
  // Steady state per tile t:
  //   ISSUE_A(t+1); STAGE_B(t+1 -> Bs[(t+1)&1])   (fly under COMPUTE)
  //   COMPUTE(t)   reads As + Bs[t&1]
  //   BAR_RAW      (As free)
  //   WRITE_A      (convert + ds_write next A tile)
  //   END_BAR      (stage visible to all)
  // t=0
  ISSUE_A(1) STAGE_B(1, 1) SB0 COMPUTE(0) BAR_RAW WRITE_A END_BAR
  // t=1
  ISSUE_A(2) STAGE_B(0, 2) SB0 COMPUTE(1) BAR_RAW WRITE_A END_BAR
  // t=2
  ISSUE_A(3) STAGE_B(1, 3) SB0 COMPUTE(0) BAR_RAW WRITE_A END_BAR
  // t=3
  ISSUE_A(4) STAGE_B(0, 4) SB0 COMPUTE(1) BAR_RAW WRITE_A END_BAR
  // t=4
  ISSUE_A(5) STAGE_B(1, 5) SB0 COMPUTE(0) BAR_RAW WRITE_A END_BAR
  // t=5
  ISSUE_A(6) STAGE_B(0, 6) SB0 COMPUTE(1) BAR_RAW WRITE_A END_BAR
  // t=6
  ISSUE_A(7) STAGE_B(1, 7) SB0 COMPUTE(0) BAR_RAW WRITE_A END_BAR
  // t=7
  COMPUTE(1)

#undef ISSUE_A
#undef STAGE_B
#undef WRITE_A
#undef COMPUTE
#undef BAR_RAW
#undef END_BAR
#undef SB0

  // ---- epilogue (C/D layout: col=lane&15, row=(lane>>4)*4+ii) ----
  const int crow0 = bx * 128 + wm + g * 4;
  const int ccol0 = by * 128 + wn + r;
#pragma unroll
  for (int j = 0; j < 4; ++j) {
    float bv = bias[ccol0 + j * 16];
#pragma unroll
    for (int i = 0; i < 4; ++i)
#pragma unroll
      for (int ii = 0; ii < 4; ++ii) acc[i][j][ii] += bv;
  }
  if (qnorm) {  // wave's 64 cols == one head; L2-norm over them per row
    const int h = (by * 128 + wn) >> 6;
    const float gam = gamma[h];
#pragma unroll
    for (int i = 0; i < 4; ++i)
#pragma unroll
      for (int ii = 0; ii < 4; ++ii) {
        float s = 0.f;
#pragma unroll
        for (int j = 0; j < 4; ++j) s += acc[i][j][ii] * acc[i][j][ii];
        s += __shfl_xor(s, 1);
        s += __shfl_xor(s, 2);
        s += __shfl_xor(s, 4);
        s += __shfl_xor(s, 8);
        float sc = gam / sqrtf(s);
#pragma unroll
        for (int j = 0; j < 4; ++j) acc[i][j][ii] *= sc;
      }
  }
#pragma unroll
  for (int i = 0; i < 4; ++i)
#pragma unroll
    for (int j = 0; j < 4; ++j)
#pragma unroll
      for (int ii = 0; ii < 4; ++ii) {
        long row = crow0 + i * 16 + ii;
        int col = ccol0 + j * 16;
        if constexpr (sizeof(CT) == 2)
          C[row * NN + col] = f2b(acc[i][j][ii]);
        else
          C[row * NN + col] = acc[i][j][ii];
      }
}

// y-inner + XCD-chunked bijective swizzle; NWG must be a multiple of 32.
DEVFN void swz_xy(int bid, int nwg, int& bx, int& by) {
  int s = (bid & 7) * (nwg >> 3) + (bid >> 3);
  bx = s >> 2;
  by = s & 3;
}

__global__ __launch_bounds__(256, 3)
void proj_qkv(const float* __restrict__ Aq, const float* __restrict__ Ak,
              const float* __restrict__ Av, const unsigned short* __restrict__ Bq,
              const unsigned short* __restrict__ Bk, const unsigned short* __restrict__ Bv,
              const float* __restrict__ bq, const float* __restrict__ bk,
              const float* __restrict__ bv, unsigned short* __restrict__ Cq,
              unsigned short* __restrict__ Ck, unsigned short* __restrict__ Cv,
              const float* __restrict__ gamma) {
  const int z = blockIdx.z;
  const float* A = z == 0 ? Aq : (z == 1 ? Ak : Av);
  const unsigned short* B = z == 0 ? Bq : (z == 1 ? Bk : Bv);
  const float* bias = z == 0 ? bq : (z == 1 ? bk : bv);
  unsigned short* C = z == 0 ? Cq : (z == 1 ? Ck : Cv);
  int bx, by;
  swz_xy(blockIdx.x, 1024, bx, by);
  gemm_core<true, unsigned short>(A, B, bias, C, z == 0, gamma, bx, by);
}

__global__ __launch_bounds__(256, 3)
void gemm_final(const unsigned short* __restrict__ q, const unsigned short* __restrict__ Mt,
                const float* __restrict__ bo, float* __restrict__ out) {
  const int zb = blockIdx.z;
  int bx, by;
  swz_xy(blockIdx.x, 128, bx, by);
  gemm_core<false, float>(q + (long)zb * 2097152, Mt + (long)zb * 262144, bo,
                          out + (long)zb * 2097152, false, nullptr, bx, by);
}

// ---------------------------------------------------------------------------
// kv partials: part[chunk][bh][dk][dv] = sum over 256 n of k outer v
// ---------------------------------------------------------------------------
#define NCHUNK 16
__global__ __launch_bounds__(256, 2)
void kv_partial(const unsigned short* __restrict__ kq,
                const unsigned short* __restrict__ vq,
                float* __restrict__ part) {
  const int tid = threadIdx.x;
  const int chunk = blockIdx.x;
  const int bh = blockIdx.y;
  const int b = bh >> 3, h = bh & 7;
  __shared__ float ks[32][64];
  __shared__ float vs[32][64];
  const int dk0 = (tid & 15) * 4;
  const int dv0 = (tid >> 4) * 4;
  float acc[4][4] = {};
  const long nbase = (long)b * 4096 + chunk * 256;

  for (int sub = 0; sub < 8; ++sub) {
    long n0 = nbase + sub * 32;
#pragma unroll
    for (int i = 0; i < 2; ++i) {
      int e = i * 256 + tid;
      int row = e >> 4, c4 = e & 15;
      long gofs = (n0 + row) * 512 + h * 64 + c4 * 4;
      u16x4 kk = *reinterpret_cast<const u16x4*>(kq + gofs);
      u16x4 vv = *reinterpret_cast<const u16x4*>(vq + gofs);
      f32x4 kf = {b2f(kk[0]), b2f(kk[1]), b2f(kk[2]), b2f(kk[3])};
      f32x4 vf = {b2f(vv[0]), b2f(vv[1]), b2f(vv[2]), b2f(vv[3])};
      *reinterpret_cast<f32x4*>(&ks[row][c4 * 4]) = kf;
      *reinterpret_cast<f32x4*>(&vs[row][c4 * 4]) = vf;
    }
    __syncthreads();
#pragma unroll 4
    for (int n = 0; n < 32; ++n) {
      f32x4 kk = *reinterpret_cast<const f32x4*>(&ks[n][dk0]);
      f32x4 vv = *reinterpret_cast<const f32x4*>(&vs[n][dv0]);
#pragma unroll
      for (int a = 0; a < 4; ++a)
#pragma unroll
        for (int c = 0; c < 4; ++c)
          acc[a][c] += kk[a] * vv[c];
    }
    __syncthreads();
  }
  float* pg = part + ((long)chunk * 64 + bh) * 4096;
#pragma unroll
  for (int a = 0; a < 4; ++a) {
    f32x4 o = {acc[a][0], acc[a][1], acc[a][2], acc[a][3]};
    *reinterpret_cast<f32x4*>(pg + (dk0 + a) * 64 + dv0) = o;
  }
}

// reduce partials + L2-norm rows (over dv) * gamma -> kvn bf16 [bh][64][64]
__global__ __launch_bounds__(256)
void kv_normN(const float* __restrict__ part, const float* __restrict__ gamma,
              unsigned short* __restrict__ kvn) {
  const int bh = blockIdx.x, h = bh & 7;
  const int tid = threadIdx.x;
  __shared__ float kvs[4096];
  __shared__ float scale[64];
#pragma unroll
  for (int i = 0; i < 4; ++i) {
    int e4 = i * 256 + tid;
    const float* p = part + (long)bh * 4096 + e4 * 4;
    f32x4 s = {0.f, 0.f, 0.f, 0.f};
#pragma unroll
    for (int c = 0; c < NCHUNK; ++c) {
      f32x4 v = *reinterpret_cast<const f32x4*>(p + (long)c * 64 * 4096);
      s += v;
    }
    *reinterpret_cast<f32x4*>(kvs + e4 * 4) = s;
  }
  __syncthreads();
  if (tid < 64) {
    float s = 0.f;
    for (int dv = 0; dv < 64; ++dv) { float x = kvs[tid * 64 + dv]; s += x * x; }
    scale[tid] = gamma[h] / sqrtf(s);
  }
  __syncthreads();
#pragma unroll
  for (int i = 0; i < 4; ++i) {
    int e4 = i * 256 + tid;
    float sc = scale[e4 >> 4];
    f32x4 v = *reinterpret_cast<const f32x4*>(kvs + e4 * 4);
    u16x4 o = {f2b(v[0] * sc), f2b(v[1] * sc), f2b(v[2] * sc), f2b(v[3] * sc)};
    *reinterpret_cast<u16x4*>(kvn + (long)bh * 4096 + e4 * 4) = o;
  }
}

// Mt[b][c][h*64+dk] = sum_dv Wo[c][h*64+dv] * kvn[b,h][dk][dv]
__global__ __launch_bounds__(64)
void mt_kernel(const unsigned short* __restrict__ Wo_b,
               const unsigned short* __restrict__ kvn,
               unsigned short* __restrict__ Mt) {
  const int bid = blockIdx.x;
  const int bh = bid >> 2, seg = bid & 3;
  const int b = bh >> 3, h = bh & 7;
  const int lane = threadIdx.x;
  const int r = lane & 15, g = lane >> 4;
  f32x4 acc[8][4] = {};
  s16x8 bf[2][4];
#pragma unroll
  for (int ks = 0; ks < 2; ++ks)
#pragma unroll
    for (int j = 0; j < 4; ++j)
      bf[ks][j] = *reinterpret_cast<const s16x8*>(
          kvn + (long)bh * 4096 + (j * 16 + r) * 64 + ks * 32 + g * 8);
#pragma unroll
  for (int ks = 0; ks < 2; ++ks)
#pragma unroll
    for (int i = 0; i < 8; ++i) {
      s16x8 af = *reinterpret_cast<const s16x8*>(
          Wo_b + (long)(seg * 128 + i * 16 + r) * 512 + h * 64 + ks * 32 + g * 8);
#pragma unroll
      for (int j = 0; j < 4; ++j)
        acc[i][j] = __builtin_amdgcn_mfma_f32_16x16x32_bf16(af, bf[ks][j], acc[i][j], 0, 0, 0);
    }
#pragma unroll
  for (int i = 0; i < 8; ++i)
#pragma unroll
    for (int j = 0; j < 4; ++j)
#pragma unroll
      for (int ii = 0; ii < 4; ++ii) {
        int c = seg * 128 + i * 16 + g * 4 + ii;
        int dk = j * 16 + r;
        Mt[(long)b * 262144 + (long)c * 512 + h * 64 + dk] = f2b(acc[i][j][ii]);
      }
}

__global__ void cast4(const float* __restrict__ a0, const float* __restrict__ a1,
                      const float* __restrict__ a2, const float* __restrict__ a3,
                      unsigned short* __restrict__ o0, unsigned short* __restrict__ o1,
                      unsigned short* __restrict__ o2, unsigned short* __restrict__ o3) {
  const int y = blockIdx.y;
  const float* in = y == 0 ? a0 : (y == 1 ? a1 : (y == 2 ? a2 : a3));
  unsigned short* out = y == 0 ? o0 : (y == 1 ? o1 : (y == 2 ? o2 : o3));
  int i = blockIdx.x * 256 + threadIdx.x;
  f32x4 v = reinterpret_cast<const f32x4*>(in)[i];
  reinterpret_cast<u16x4*>(out)[i] = u16x4{f2b(v[0]), f2b(v[1]), f2b(v[2]), f2b(v[3])};
}

// ---------------------------------------------------------------------------
extern "C" void kernel_launch(void* const* d_in, const int* in_sizes, int n_in,
                              void* d_out, int out_size, void* d_ws, size_t ws_size,
                              hipStream_t stream) {
  const float* queries = (const float*)d_in[0];
  const float* keys    = (const float*)d_in[1];
  const float* values  = (const float*)d_in[2];
  const float* Wq = (const float*)d_in[3];
  const float* bq = (const float*)d_in[4];
  const float* Wk = (const float*)d_in[5];
  const float* bk = (const float*)d_in[6];
  const float* Wv = (const float*)d_in[7];
  const float* bv = (const float*)d_in[8];
  const float* Wo = (const float*)d_in[9];
  const float* bo = (const float*)d_in[10];
  const float* gamma = (const float*)d_in[11];

  unsigned short* Wq_b = (unsigned short*)d_ws;            // 512 KB each
  unsigned short* Wk_b = Wq_b + 262144;
  unsigned short* Wv_b = Wk_b + 262144;
  unsigned short* Wo_b = Wv_b + 262144;
  unsigned short* q_b  = Wo_b + 262144;                    // 32 MB (holds q_n)
  unsigned short* kvn  = q_b + 16777216;                   // 512 KB
  float* part = (float*)(kvn + 262144);                    // 16 MB
  unsigned short* Mt = (unsigned short*)part;              // 4 MB (part dead by then)
  unsigned short* k_b = (unsigned short*)d_out;            // d_out scratch
  unsigned short* v_b = k_b + 16777216;
  float* out = (float*)d_out;

  cast4<<<dim3(256, 4), 256, 0, stream>>>(Wq, Wk, Wv, Wo, Wq_b, Wk_b, Wv_b, Wo_b);

  proj_qkv<<<dim3(1024, 1, 3), 256, 0, stream>>>(
      queries, keys, values, Wq_b, Wk_b, Wv_b, bq, bk, bv, q_b, k_b, v_b, gamma);

  kv_partial<<<dim3(NCHUNK, 64), 256, 0, stream>>>(k_b, v_b, part);
  kv_normN<<<64, 256, 0, stream>>>(part, gamma, kvn);
  mt_kernel<<<256, 64, 0, stream>>>(Wo_b, kvn, Mt);

  gemm_final<<<dim3(128, 1, 8), 256, 0, stream>>>(q_b, Mt, bo, out);
}